// Round 1
// baseline (30712.430 us; speedup 1.0000x reference)
//
#include <hip/hip_runtime.h>

#define TDIM 512
#define BDIM 256
#define IDIM 64
#define HDIM 512

constexpr int GROUP = 32;   // col-blocks per batch group

typedef short bf16x8 __attribute__((ext_vector_type(8)));
typedef float f32x4  __attribute__((ext_vector_type(4)));

__device__ __forceinline__ unsigned short f2bf(float f) {
  union { float f; unsigned u; } v; v.f = f;
  unsigned r = (v.u + 0x7fffu + ((v.u >> 16) & 1u)) >> 16;
  return (unsigned short)r;
}

__device__ __forceinline__ bf16x8 load8f_bf16(const float* p) {
  float4 a = *(const float4*)p;
  float4 b = *(const float4*)(p + 4);
  bf16x8 r;
  r[0] = (short)f2bf(a.x); r[1] = (short)f2bf(a.y);
  r[2] = (short)f2bf(a.z); r[3] = (short)f2bf(a.w);
  r[4] = (short)f2bf(b.x); r[5] = (short)f2bf(b.y);
  r[6] = (short)f2bf(b.z); r[7] = (short)f2bf(b.w);
  return r;
}

__device__ __forceinline__ float sigm(float x)   { return 1.0f / (1.0f + __expf(-x)); }
__device__ __forceinline__ float tanh_f(float x) { return 2.0f / (1.0f + __expf(-2.0f * x)) - 1.0f; }

__device__ __forceinline__ void spin_ge(int* f, int target) {
  while (__hip_atomic_load(f, __ATOMIC_RELAXED, __HIP_MEMORY_SCOPE_AGENT) < target)
    __builtin_amdgcn_s_sleep(1);
  __builtin_amdgcn_fence(__ATOMIC_ACQUIRE, "agent");
}

// Persistent 2-layer LSTM. 256 blocks x 256 threads, 1 block/CU.
// Block (bi = bid&7, hj = bid>>3): batch rows [bi*32, bi*32+32), hidden cols [hj*16, hj*16+16).
// hcat[2][256][1024] bf16: cols 0-511 = h0 (parity t&1), cols 512-1023 = h1 (parity (t+1)&1, shifted).
__global__ __launch_bounds__(256, 1)
void lstm_persist(const float* __restrict__ x,
                  const float* __restrict__ Wih0, const float* __restrict__ Whh0,
                  const float* __restrict__ bih0, const float* __restrict__ bhh0,
                  const float* __restrict__ Wih1, const float* __restrict__ Whh1,
                  const float* __restrict__ bih1, const float* __restrict__ bhh1,
                  unsigned short* __restrict__ hcat, float* __restrict__ h1f,
                  int* __restrict__ flags)
{
  const int tid  = threadIdx.x;
  const int w    = tid >> 6;          // wave 0..3
  const int lane = tid & 63;
  const int lrow = lane & 15;         // m/n index within fragment
  const int lk8  = (lane >> 4) << 3;  // k offset within 32-chunk
  const int bid  = blockIdx.x;
  const int bi   = bid & 7;           // batch group (XCD-colocated)
  const int hj   = bid >> 3;          // col block 0..31

  int* flag0 = flags + bi * 32;
  int* flag1 = flags + 512 + bi * 32;

  __shared__ float part[4 * 64 * 36];   // [wave][gatecol 64][row 32 pad->36]

  // ---------------- weights -> registers (bf16 fragments), once ----------------
  // layer0: K = 64(x) + 512(h) = 18 chunks; layer1: K = 512(h0)+512(h1) = 32 chunks.
  // wave w owns chunks {w, w+4, w+8, ...}.
  const int count0 = (w < 2) ? 5 : 4;
  bf16x8 bw0[5][4];
  bf16x8 bw1[8][4];
  #pragma unroll
  for (int s = 0; s < 5; ++s) {
    #pragma unroll
    for (int g = 0; g < 4; ++g) {
      int c = w + 4 * s;
      if (s < count0) {
        int j = g * 512 + hj * 16 + lrow;
        const float* src = (c < 2) ? (Wih0 + (size_t)j * 64  + (c * 32 + lk8))
                                   : (Whh0 + (size_t)j * 512 + (c * 32 - 64 + lk8));
        bw0[s][g] = load8f_bf16(src);
      } else {
        bf16x8 z = {0,0,0,0,0,0,0,0};
        bw0[s][g] = z;
      }
    }
  }
  #pragma unroll
  for (int s = 0; s < 8; ++s) {
    #pragma unroll
    for (int g = 0; g < 4; ++g) {
      int c = w + 4 * s;
      int j = g * 512 + hj * 16 + lrow;
      const float* src = (c < 16) ? (Wih1 + (size_t)j * 512 + (c * 32 + lk8))
                                  : (Whh1 + (size_t)j * 512 + (c * 32 - 512 + lk8));
      bw1[s][g] = load8f_bf16(src);
    }
  }

  // ---------------- per-thread bias + cell bookkeeping ----------------
  const int hc   = tid & 15;          // hidden col within tile
  const int r_lo = tid >> 4;          // 0..15 (cells r_lo and r_lo+16)
  const int jcol = hj * 16 + hc;      // global hidden col
  float bia0[4], bia1[4];
  #pragma unroll
  for (int g = 0; g < 4; ++g) {
    bia0[g] = bih0[g * 512 + jcol] + bhh0[g * 512 + jcol];
    bia1[g] = bih1[g * 512 + jcol] + bhh1[g * 512 + jcol];
  }

  float c0s[2] = {0.f, 0.f}, c1s[2] = {0.f, 0.f};

  const size_t HROW = 1024;
  const size_t HBUF = (size_t)BDIM * HROW;
  const int r0w = ((lane >> 4) << 2);

  #pragma unroll 1
  for (int t = 0; t < TDIM; ++t) {
    // ======================= layer 0 =======================
    spin_ge(flag0, GROUP * t);                       // group finished writing h0[t-1]
    f32x4 acc[2][4];
    #pragma unroll
    for (int m = 0; m < 2; ++m)
      #pragma unroll
      for (int g = 0; g < 4; ++g) { f32x4 z = {0.f,0.f,0.f,0.f}; acc[m][g] = z; }

    const unsigned short* hprev = hcat + (size_t)((t + 1) & 1) * HBUF;
    #pragma unroll
    for (int s = 0; s < 5; ++s) {
      int c = w + 4 * s;
      if (s < count0) {
        bf16x8 a[2];
        #pragma unroll
        for (int m = 0; m < 2; ++m) {
          int brow = bi * 32 + m * 16 + lrow;
          if (c < 2) {
            a[m] = load8f_bf16(x + ((size_t)brow * TDIM + t) * IDIM + (c * 32 + lk8));
          } else {
            a[m] = *(const bf16x8*)(hprev + (size_t)brow * HROW + (c * 32 - 64 + lk8));
          }
        }
        #pragma unroll
        for (int m = 0; m < 2; ++m)
          #pragma unroll
          for (int g = 0; g < 4; ++g)
            acc[m][g] = __builtin_amdgcn_mfma_f32_16x16x32_bf16(a[m], bw0[s][g], acc[m][g], 0, 0, 0);
      }
    }
    #pragma unroll
    for (int m = 0; m < 2; ++m)
      #pragma unroll
      for (int g = 0; g < 4; ++g)
        *(f32x4*)&part[(w * 64 + g * 16 + lrow) * 36 + m * 16 + r0w] = acc[m][g];
    __syncthreads();

    unsigned short* hcur = hcat + (size_t)(t & 1) * HBUF;
    #pragma unroll
    for (int cc = 0; cc < 2; ++cc) {
      int r = r_lo + cc * 16;
      float gv[4];
      #pragma unroll
      for (int g = 0; g < 4; ++g) {
        float sum = bia0[g];
        #pragma unroll
        for (int w4 = 0; w4 < 4; ++w4)
          sum += part[(w4 * 64 + g * 16 + hc) * 36 + r];
        gv[g] = sum;
      }
      float ig = sigm(gv[0]), fg = sigm(gv[1]), gg = tanh_f(gv[2]), og = sigm(gv[3]);
      c0s[cc] = fg * c0s[cc] + ig * gg;
      float hv = og * tanh_f(c0s[cc]);
      hcur[(size_t)(bi * 32 + r) * HROW + jcol] = f2bf(hv);
    }
    __builtin_amdgcn_fence(__ATOMIC_RELEASE, "agent");
    __syncthreads();
    if (tid == 0) __hip_atomic_fetch_add(flag0, 1, __ATOMIC_RELEASE, __HIP_MEMORY_SCOPE_AGENT);

    // ======================= layer 1 =======================
    spin_ge(flag0, GROUP * (t + 1));                 // h0[t] complete across group
    spin_ge(flag1, GROUP * t);                       // h1[t-1] complete across group
    #pragma unroll
    for (int m = 0; m < 2; ++m)
      #pragma unroll
      for (int g = 0; g < 4; ++g) { f32x4 z = {0.f,0.f,0.f,0.f}; acc[m][g] = z; }

    const unsigned short* hsrc = hcat + (size_t)(t & 1) * HBUF;   // [h0[t] | h1[t-1]]
    #pragma unroll
    for (int s = 0; s < 8; ++s) {
      int c = w + 4 * s;
      bf16x8 a[2];
      #pragma unroll
      for (int m = 0; m < 2; ++m) {
        int brow = bi * 32 + m * 16 + lrow;
        a[m] = *(const bf16x8*)(hsrc + (size_t)brow * HROW + (c * 32 + lk8));
      }
      #pragma unroll
      for (int m = 0; m < 2; ++m)
        #pragma unroll
        for (int g = 0; g < 4; ++g)
          acc[m][g] = __builtin_amdgcn_mfma_f32_16x16x32_bf16(a[m], bw1[s][g], acc[m][g], 0, 0, 0);
    }
    #pragma unroll
    for (int m = 0; m < 2; ++m)
      #pragma unroll
      for (int g = 0; g < 4; ++g)
        *(f32x4*)&part[(w * 64 + g * 16 + lrow) * 36 + m * 16 + r0w] = acc[m][g];
    __syncthreads();

    unsigned short* hnext = hcat + (size_t)((t + 1) & 1) * HBUF;
    #pragma unroll
    for (int cc = 0; cc < 2; ++cc) {
      int r = r_lo + cc * 16;
      float gv[4];
      #pragma unroll
      for (int g = 0; g < 4; ++g) {
        float sum = bia1[g];
        #pragma unroll
        for (int w4 = 0; w4 < 4; ++w4)
          sum += part[(w4 * 64 + g * 16 + hc) * 36 + r];
        gv[g] = sum;
      }
      float ig = sigm(gv[0]), fg = sigm(gv[1]), gg = tanh_f(gv[2]), og = sigm(gv[3]);
      c1s[cc] = fg * c1s[cc] + ig * gg;
      float hv = og * tanh_f(c1s[cc]);
      hnext[(size_t)(bi * 32 + r) * HROW + 512 + jcol] = f2bf(hv);
      if (t == TDIM - 1) h1f[(size_t)(bi * 32 + r) * HDIM + jcol] = hv;
    }
    __builtin_amdgcn_fence(__ATOMIC_RELEASE, "agent");
    __syncthreads();
    if (tid == 0) __hip_atomic_fetch_add(flag1, 1, __ATOMIC_RELEASE, __HIP_MEMORY_SCOPE_AGENT);
  }
}

// out[b] = h1f[b,:] . Wlin + blin ; out[256] = mean((out - y)^2)
__global__ void head_k(const float* __restrict__ h1f, const float* __restrict__ Wlin,
                       const float* __restrict__ blin, const float* __restrict__ y,
                       float* __restrict__ dout)
{
  __shared__ float red[256];
  int b = threadIdx.x;
  const float4* hp = (const float4*)(h1f + (size_t)b * HDIM);
  const float4* wp = (const float4*)Wlin;
  float acc = 0.f;
  #pragma unroll 8
  for (int i = 0; i < HDIM / 4; ++i) {
    float4 h4 = hp[i]; float4 w4 = wp[i];
    acc += h4.x * w4.x + h4.y * w4.y + h4.z * w4.z + h4.w * w4.w;
  }
  float o = acc + blin[0];
  dout[b] = o;
  float d = o - y[b];
  red[b] = d * d;
  __syncthreads();
  for (int off = 128; off > 0; off >>= 1) {
    if (b < off) red[b] += red[b + off];
    __syncthreads();
  }
  if (b == 0) dout[256] = red[0] * (1.0f / 256.0f);
}

extern "C" void kernel_launch(void* const* d_in, const int* in_sizes, int n_in,
                              void* d_out, int out_size, void* d_ws, size_t ws_size,
                              hipStream_t stream)
{
  const float* x    = (const float*)d_in[0];
  const float* y    = (const float*)d_in[1];
  const float* Wih0 = (const float*)d_in[2];
  const float* Whh0 = (const float*)d_in[3];
  const float* bih0 = (const float*)d_in[4];
  const float* bhh0 = (const float*)d_in[5];
  const float* Wih1 = (const float*)d_in[6];
  const float* Whh1 = (const float*)d_in[7];
  const float* bih1 = (const float*)d_in[8];
  const float* bhh1 = (const float*)d_in[9];
  const float* Wlin = (const float*)d_in[10];
  const float* blin = (const float*)d_in[11];

  char* ws = (char*)d_ws;
  unsigned short* hcat = (unsigned short*)ws;          // 2*256*1024*2 = 1,048,576 B
  int*   flags = (int*)(ws + 1048576);                 // 4096 B (padded counters)
  float* h1f   = (float*)(ws + 1048576 + 4096);        // 256*512*4 = 524,288 B

  // zero hcat (h[-1] = 0) and flags every call (graph-replay safe)
  hipMemsetAsync(d_ws, 0, 1048576 + 4096, stream);

  hipLaunchKernelGGL(lstm_persist, dim3(256), dim3(256), 0, stream,
                     x, Wih0, Whh0, bih0, bhh0, Wih1, Whh1, bih1, bhh1,
                     hcat, h1f, flags);
  hipLaunchKernelGGL(head_k, dim3(1), dim3(256), 0, stream,
                     h1f, Wlin, blin, y, (float*)d_out);
}

// Round 2
// 6110.714 us; speedup vs baseline: 5.0260x; 5.0260x over previous
//
#include <hip/hip_runtime.h>

#define TDIM 512
#define BDIM 256
#define IDIM 64
#define HDIM 512

typedef short bf16x8 __attribute__((ext_vector_type(8)));
typedef float f32x4  __attribute__((ext_vector_type(4)));

__device__ __forceinline__ unsigned short f2bf(float f) {
  union { float f; unsigned u; } v; v.f = f;
  return (unsigned short)((v.u + 0x7fffu + ((v.u >> 16) & 1u)) >> 16);
}

__device__ __forceinline__ bf16x8 load8f_bf16(const float* p) {
  float4 a = *(const float4*)p;
  float4 b = *(const float4*)(p + 4);
  bf16x8 r;
  r[0] = (short)f2bf(a.x); r[1] = (short)f2bf(a.y);
  r[2] = (short)f2bf(a.z); r[3] = (short)f2bf(a.w);
  r[4] = (short)f2bf(b.x); r[5] = (short)f2bf(b.y);
  r[6] = (short)f2bf(b.z); r[7] = (short)f2bf(b.w);
  return r;
}

// device-coherent 16B read of 8 bf16: two 8B agent-scope relaxed atomic loads.
// Compiles to global_load_dwordx2 sc0 sc1 -> bypasses (possibly stale) L1/L2,
// served by the coherent MALL. No cache-maintenance fences required.
__device__ __forceinline__ bf16x8 load_h16(const unsigned short* p) {
  union { unsigned long long u[2]; bf16x8 v; } r;
  r.u[0] = __hip_atomic_load((const unsigned long long*)p,
                             __ATOMIC_RELAXED, __HIP_MEMORY_SCOPE_AGENT);
  r.u[1] = __hip_atomic_load((const unsigned long long*)(p + 4),
                             __ATOMIC_RELAXED, __HIP_MEMORY_SCOPE_AGENT);
  return r.v;
}

__device__ __forceinline__ float sigm(float x)   { return 1.0f / (1.0f + __expf(-x)); }
__device__ __forceinline__ float tanh_f(float x) { return 2.0f / (1.0f + __expf(-2.0f * x)) - 1.0f; }

// wait until all 32 per-block words >= target (lanes 0-31 each poll one word)
__device__ __forceinline__ void wait_words(const int* base, int target) {
  const int l = threadIdx.x & 63;
  const int* p = base + (l & 31);
  while (true) {
    int v = __hip_atomic_load(p, __ATOMIC_RELAXED, __HIP_MEMORY_SCOPE_AGENT);
    if (__all(v >= target)) break;
    __builtin_amdgcn_s_sleep(2);
  }
  asm volatile("" ::: "memory");   // keep h loads below the spin
}

// combined wait: lanes 0-31 poll w0 (>= tgt0), lanes 32-63 poll w1 (>= tgt1)
__device__ __forceinline__ void wait_words2(const int* w0, const int* w1, int tgt0, int tgt1) {
  const int l = threadIdx.x & 63;
  const int* p  = (l < 32) ? (w0 + l) : (w1 + (l - 32));
  const int tgt = (l < 32) ? tgt0 : tgt1;
  while (true) {
    int v = __hip_atomic_load(p, __ATOMIC_RELAXED, __HIP_MEMORY_SCOPE_AGENT);
    if (__all(v >= tgt)) break;
    __builtin_amdgcn_s_sleep(2);
  }
  asm volatile("" ::: "memory");
}

// Persistent 2-layer LSTM. 256 blocks x 256 threads, 1 block/CU.
// Block (bi = bid&7, hj = bid>>3): batch rows [bi*32,+32), hidden cols [hj*16,+16).
// hcat[2][256][1024] bf16: cols 0-511 = h0 (parity t&1), cols 512-1023 = h1 (parity (t+1)&1).
// Sync: per-block monotone words (words0/words1[bi][hj]), no atomics RMW, no cache fences;
// all cross-block data moves via sc0/sc1 (agent-scope relaxed atomic) accesses through MALL.
__global__ __launch_bounds__(256, 1)
void lstm_persist(const float* __restrict__ x,
                  const float* __restrict__ Wih0, const float* __restrict__ Whh0,
                  const float* __restrict__ bih0, const float* __restrict__ bhh0,
                  const float* __restrict__ Wih1, const float* __restrict__ Whh1,
                  const float* __restrict__ bih1, const float* __restrict__ bhh1,
                  unsigned short* __restrict__ hcat, float* __restrict__ h1f,
                  int* __restrict__ flags)
{
  const int tid  = threadIdx.x;
  const int w    = tid >> 6;          // wave 0..3
  const int lane = tid & 63;
  const int lrow = lane & 15;         // m/n index within fragment
  const int lk8  = (lane >> 4) << 3;  // k offset within 32-chunk
  const int bid  = blockIdx.x;
  const int bi   = bid & 7;           // batch group
  const int hj   = bid >> 3;          // col block 0..31

  int* words0 = flags + bi * 64;       // [32] layer0 progress per col-block
  int* words1 = flags + bi * 64 + 32;  // [32] layer1 progress per col-block

  __shared__ float part[4 * 64 * 36];  // [wave][gatecol 64][row 32 pad->36]

  // ---------------- weights -> registers (bf16 fragments), once ----------------
  const int count0 = (w < 2) ? 5 : 4;
  bf16x8 bw0[5][4];
  bf16x8 bw1[8][4];
  #pragma unroll
  for (int s = 0; s < 5; ++s) {
    #pragma unroll
    for (int g = 0; g < 4; ++g) {
      int c = w + 4 * s;
      if (s < count0) {
        int j = g * 512 + hj * 16 + lrow;
        const float* src = (c < 2) ? (Wih0 + (size_t)j * 64  + (c * 32 + lk8))
                                   : (Whh0 + (size_t)j * 512 + (c * 32 - 64 + lk8));
        bw0[s][g] = load8f_bf16(src);
      } else {
        bf16x8 z = {0,0,0,0,0,0,0,0};
        bw0[s][g] = z;
      }
    }
  }
  #pragma unroll
  for (int s = 0; s < 8; ++s) {
    #pragma unroll
    for (int g = 0; g < 4; ++g) {
      int c = w + 4 * s;
      int j = g * 512 + hj * 16 + lrow;
      const float* src = (c < 16) ? (Wih1 + (size_t)j * 512 + (c * 32 + lk8))
                                  : (Whh1 + (size_t)j * 512 + (c * 32 - 512 + lk8));
      bw1[s][g] = load8f_bf16(src);
    }
  }

  // ---------------- epilogue mapping: thread = (row r, col-pair hp) ----------------
  const int hp  = tid & 7;            // col pair 0..7
  const int r   = tid >> 3;           // batch row within tile 0..31
  const int jc0 = hj * 16 + 2 * hp;   // even global hidden col
  const int grow = bi * 32 + r;       // global batch row
  float bia0[2][4], bia1[2][4];
  #pragma unroll
  for (int cc = 0; cc < 2; ++cc)
    #pragma unroll
    for (int g = 0; g < 4; ++g) {
      bia0[cc][g] = bih0[g * 512 + jc0 + cc] + bhh0[g * 512 + jc0 + cc];
      bia1[cc][g] = bih1[g * 512 + jc0 + cc] + bhh1[g * 512 + jc0 + cc];
    }

  float c0s[2] = {0.f, 0.f}, c1s[2] = {0.f, 0.f};

  const size_t HROW = 1024;
  const size_t HBUF = (size_t)BDIM * HROW;
  const int r0w = ((lane >> 4) << 2);
  const int s0 = (w < 2) ? 1 : 0;     // h-chunk start index in bw0

  #pragma unroll 1
  for (int t = 0; t < TDIM; ++t) {
    // ======================= layer 0 =======================
    f32x4 acc[2][4];
    #pragma unroll
    for (int m = 0; m < 2; ++m)
      #pragma unroll
      for (int g = 0; g < 4; ++g) { f32x4 z = {0.f,0.f,0.f,0.f}; acc[m][g] = z; }

    // x-chunk MFMAs have no h dependency: do them BEFORE the spin
    if (w < 2) {
      bf16x8 a[2];
      #pragma unroll
      for (int m = 0; m < 2; ++m)
        a[m] = load8f_bf16(x + ((size_t)(bi * 32 + m * 16 + lrow) * TDIM + t) * IDIM + (w * 32 + lk8));
      #pragma unroll
      for (int m = 0; m < 2; ++m)
        #pragma unroll
        for (int g = 0; g < 4; ++g)
          acc[m][g] = __builtin_amdgcn_mfma_f32_16x16x32_bf16(a[m], bw0[0][g], acc[m][g], 0, 0, 0);
    }

    wait_words(words0, t);                       // h0[t-1] complete across group
    const unsigned short* hprev = hcat + (size_t)((t + 1) & 1) * HBUF;
    #pragma unroll
    for (int s = 0; s < 5; ++s) {
      if (s >= s0 && s < count0) {
        int c = w + 4 * s;
        bf16x8 a[2];
        #pragma unroll
        for (int m = 0; m < 2; ++m)
          a[m] = load_h16(hprev + (size_t)(bi * 32 + m * 16 + lrow) * HROW + (c * 32 - 64 + lk8));
        #pragma unroll
        for (int m = 0; m < 2; ++m)
          #pragma unroll
          for (int g = 0; g < 4; ++g)
            acc[m][g] = __builtin_amdgcn_mfma_f32_16x16x32_bf16(a[m], bw0[s][g], acc[m][g], 0, 0, 0);
      }
    }
    #pragma unroll
    for (int m = 0; m < 2; ++m)
      #pragma unroll
      for (int g = 0; g < 4; ++g)
        *(f32x4*)&part[(w * 64 + g * 16 + lrow) * 36 + m * 16 + r0w] = acc[m][g];
    __syncthreads();

    unsigned short* hcur = hcat + (size_t)(t & 1) * HBUF;
    {
      float hv[2];
      #pragma unroll
      for (int cc = 0; cc < 2; ++cc) {
        int hc = 2 * hp + cc;
        float gv[4];
        #pragma unroll
        for (int g = 0; g < 4; ++g) {
          float sum = bia0[cc][g];
          #pragma unroll
          for (int w4 = 0; w4 < 4; ++w4)
            sum += part[(w4 * 64 + g * 16 + hc) * 36 + r];
          gv[g] = sum;
        }
        float ig = sigm(gv[0]), fg = sigm(gv[1]), gg = tanh_f(gv[2]), og = sigm(gv[3]);
        c0s[cc] = fg * c0s[cc] + ig * gg;
        hv[cc] = og * tanh_f(c0s[cc]);
      }
      unsigned packed = (unsigned)f2bf(hv[0]) | ((unsigned)f2bf(hv[1]) << 16);
      __hip_atomic_store((unsigned*)(hcur + (size_t)grow * HROW + jc0), packed,
                         __ATOMIC_RELAXED, __HIP_MEMORY_SCOPE_AGENT);
    }
    asm volatile("s_waitcnt vmcnt(0)" ::: "memory");  // sc1 stores device-visible
    __syncthreads();                                  // all waves drained (+ LDS WAR)
    if (tid == 0)
      __hip_atomic_store(&words0[hj], t + 1, __ATOMIC_RELAXED, __HIP_MEMORY_SCOPE_AGENT);

    // ======================= layer 1 =======================
    wait_words2(words0, words1, t + 1, t);       // h0[t] and h1[t-1] complete
    #pragma unroll
    for (int m = 0; m < 2; ++m)
      #pragma unroll
      for (int g = 0; g < 4; ++g) { f32x4 z = {0.f,0.f,0.f,0.f}; acc[m][g] = z; }

    const unsigned short* hsrc = hcat + (size_t)(t & 1) * HBUF;   // [h0[t] | h1[t-1]]
    #pragma unroll
    for (int s = 0; s < 8; ++s) {
      int c = w + 4 * s;
      bf16x8 a[2];
      #pragma unroll
      for (int m = 0; m < 2; ++m)
        a[m] = load_h16(hsrc + (size_t)(bi * 32 + m * 16 + lrow) * HROW + (c * 32 + lk8));
      #pragma unroll
      for (int m = 0; m < 2; ++m)
        #pragma unroll
        for (int g = 0; g < 4; ++g)
          acc[m][g] = __builtin_amdgcn_mfma_f32_16x16x32_bf16(a[m], bw1[s][g], acc[m][g], 0, 0, 0);
    }
    #pragma unroll
    for (int m = 0; m < 2; ++m)
      #pragma unroll
      for (int g = 0; g < 4; ++g)
        *(f32x4*)&part[(w * 64 + g * 16 + lrow) * 36 + m * 16 + r0w] = acc[m][g];
    __syncthreads();

    unsigned short* hnext = hcat + (size_t)((t + 1) & 1) * HBUF;
    {
      float hv[2];
      #pragma unroll
      for (int cc = 0; cc < 2; ++cc) {
        int hc = 2 * hp + cc;
        float gv[4];
        #pragma unroll
        for (int g = 0; g < 4; ++g) {
          float sum = bia1[cc][g];
          #pragma unroll
          for (int w4 = 0; w4 < 4; ++w4)
            sum += part[(w4 * 64 + g * 16 + hc) * 36 + r];
          gv[g] = sum;
        }
        float ig = sigm(gv[0]), fg = sigm(gv[1]), gg = tanh_f(gv[2]), og = sigm(gv[3]);
        c1s[cc] = fg * c1s[cc] + ig * gg;
        hv[cc] = og * tanh_f(c1s[cc]);
      }
      unsigned packed = (unsigned)f2bf(hv[0]) | ((unsigned)f2bf(hv[1]) << 16);
      __hip_atomic_store((unsigned*)(hnext + (size_t)grow * HROW + 512 + jc0), packed,
                         __ATOMIC_RELAXED, __HIP_MEMORY_SCOPE_AGENT);
      if (t == TDIM - 1) {
        float2 o; o.x = hv[0]; o.y = hv[1];
        *(float2*)(h1f + (size_t)grow * HDIM + jc0) = o;
      }
    }
    asm volatile("s_waitcnt vmcnt(0)" ::: "memory");
    __syncthreads();
    if (tid == 0)
      __hip_atomic_store(&words1[hj], t + 1, __ATOMIC_RELAXED, __HIP_MEMORY_SCOPE_AGENT);
  }
}

// out[b] = h1f[b,:] . Wlin + blin ; out[256] = mean((out - y)^2)
__global__ void head_k(const float* __restrict__ h1f, const float* __restrict__ Wlin,
                       const float* __restrict__ blin, const float* __restrict__ y,
                       float* __restrict__ dout)
{
  __shared__ float red[256];
  int b = threadIdx.x;
  const float4* hp = (const float4*)(h1f + (size_t)b * HDIM);
  const float4* wp = (const float4*)Wlin;
  float acc = 0.f;
  #pragma unroll 8
  for (int i = 0; i < HDIM / 4; ++i) {
    float4 h4 = hp[i]; float4 w4 = wp[i];
    acc += h4.x * w4.x + h4.y * w4.y + h4.z * w4.z + h4.w * w4.w;
  }
  float o = acc + blin[0];
  dout[b] = o;
  float d = o - y[b];
  red[b] = d * d;
  __syncthreads();
  for (int off = 128; off > 0; off >>= 1) {
    if (b < off) red[b] += red[b + off];
    __syncthreads();
  }
  if (b == 0) dout[256] = red[0] * (1.0f / 256.0f);
}

extern "C" void kernel_launch(void* const* d_in, const int* in_sizes, int n_in,
                              void* d_out, int out_size, void* d_ws, size_t ws_size,
                              hipStream_t stream)
{
  const float* x    = (const float*)d_in[0];
  const float* y    = (const float*)d_in[1];
  const float* Wih0 = (const float*)d_in[2];
  const float* Whh0 = (const float*)d_in[3];
  const float* bih0 = (const float*)d_in[4];
  const float* bhh0 = (const float*)d_in[5];
  const float* Wih1 = (const float*)d_in[6];
  const float* Whh1 = (const float*)d_in[7];
  const float* bih1 = (const float*)d_in[8];
  const float* bhh1 = (const float*)d_in[9];
  const float* Wlin = (const float*)d_in[10];
  const float* blin = (const float*)d_in[11];

  char* ws = (char*)d_ws;
  unsigned short* hcat = (unsigned short*)ws;          // 2*256*1024*2 = 1,048,576 B
  int*   flags = (int*)(ws + 1048576);                 // 8 groups * 64 words = 2 KB
  float* h1f   = (float*)(ws + 1048576 + 4096);        // 256*512*4 = 524,288 B

  // zero hcat (h[-1]=0) and flag words every call (graph-replay safe)
  hipMemsetAsync(d_ws, 0, 1048576 + 4096, stream);

  hipLaunchKernelGGL(lstm_persist, dim3(256), dim3(256), 0, stream,
                     x, Wih0, Whh0, bih0, bhh0, Wih1, Whh1, bih1, bhh1,
                     hcat, h1f, flags);
  hipLaunchKernelGGL(head_k, dim3(1), dim3(256), 0, stream,
                     h1f, Wlin, blin, y, (float*)d_out);
}